// Round 5
// baseline (423.103 us; speedup 1.0000x reference)
//
#include <hip/hip_runtime.h>
#include <hip/hip_bf16.h>
#include <cstddef>

#define NHOP 10
#define NN 200000
#define FF 128
#define HIDD 256
#define CCC 100
#define NEG_SLOPE_C 0.2f

typedef __attribute__((ext_vector_type(8))) short bf16x8;   // 8 bf16 = 4 VGPR
typedef __attribute__((ext_vector_type(4))) short bf16x4;
typedef __attribute__((ext_vector_type(4))) float f32x4;

__device__ __forceinline__ short f2bfs(float x){
  return __builtin_bit_cast(short, __float2bfloat16(x));    // native v_cvt, RNE
}
__device__ __forceinline__ float bf2f(short s){
  return __uint_as_float(((unsigned)(unsigned short)s) << 16);
}
__device__ __forceinline__ f32x4 mfma16(bf16x8 a, bf16x8 b, f32x4 c){
  return __builtin_amdgcn_mfma_f32_16x16x32_bf16(a, b, c, 0, 0, 0);
}
__device__ __forceinline__ float leakyf(float x){ return x >= 0.f ? x : NEG_SLOPE_C*x; }

// ---------------- Kernel 0: weight prep (bf16 + transpose + pad) ----------------
__global__ __launch_bounds__(256) void prep_weights(
    const float* __restrict__ Wo1, const float* __restrict__ Wl1,
    const float* __restrict__ Wo2, const float* __restrict__ Wl2,
    unsigned short* __restrict__ Wo1T, unsigned short* __restrict__ Wl1T,
    unsigned short* __restrict__ Wo2T, unsigned short* __restrict__ Wl2T)
{
  const int id = blockIdx.x*256 + threadIdx.x;          // 0..32767
  {
    const int c = id >> 7, k = id & 127;                // layout [256][128]
    Wo1T[id] = (unsigned short)f2bfs(Wo1[(size_t)k*HIDD + c]);           // Wo1 [128][256]
    Wl1T[id] = (k < CCC) ? (unsigned short)f2bfs(Wl1[(size_t)k*HIDD + c]) : 0;  // pad k
  }
  if (id < 112*256){
    const int c = id >> 8, k = id & 255;                // layout [112][256]
    Wo2T[id] = (c < CCC) ? (unsigned short)f2bfs(Wo2[(size_t)k*CCC + c]) : 0;   // pad c
    Wl2T[id] = (c < CCC) ? (unsigned short)f2bfs(Wl2[(size_t)k*CCC + c]) : 0;
  }
}

// ---------------- MLP helpers (swizzled-LDS MFMA) ----------------
__device__ __forceinline__ void scatter_h(unsigned short* sH, f32x4 h, float bias,
                                          float alpha, int c, int nt, int lq)
{
  #pragma unroll
  for (int j=0;j<4;++j){
    float v = h[j] + bias;
    v = v >= 0.f ? v : alpha*v;
    const int n = nt*16 + lq*4 + j;
    *reinterpret_cast<unsigned short*>((char*)sH + n*512 + ((2*c) ^ ((n&7)<<4))) =
        (unsigned short)f2bfs(v);
  }
}

__device__ __forceinline__ void gemm1(const unsigned short* sA, unsigned short* sH,
    const unsigned short* __restrict__ W1T, const float* __restrict__ b1, const float alpha,
    const int w, const int lr, const int lq)
{
  #pragma unroll
  for (int cc=0; cc<2; ++cc){
    bf16x8 B[2][4];
    float b1c[2];
    #pragma unroll
    for (int ct=0; ct<2; ++ct){
      const int c = (w*4 + cc*2 + ct)*16 + lr;
      b1c[ct] = b1[c];
      #pragma unroll
      for (int kk=0; kk<4; ++kk)
        B[ct][kk] = *reinterpret_cast<const bf16x8*>(W1T + (size_t)c*128 + kk*32 + lq*8);
    }
    #pragma unroll
    for (int nt=0; nt<4; ++nt){
      const int row = nt*16 + lr;
      f32x4 h0 = (f32x4){0.f,0.f,0.f,0.f}, h1 = h0;
      #pragma unroll
      for (int kk=0; kk<4; ++kk){
        const bf16x8 a = *reinterpret_cast<const bf16x8*>(
            (const char*)sA + row*256 + ((kk*64 + lq*16) ^ ((row&7)<<4)));
        h0 = mfma16(a, B[0][kk], h0);
        h1 = mfma16(a, B[1][kk], h1);
      }
      scatter_h(sH, h0, b1c[0], alpha, (w*4 + cc*2 + 0)*16 + lr, nt, lq);
      scatter_h(sH, h1, b1c[1], alpha, (w*4 + cc*2 + 1)*16 + lr, nt, lq);
    }
  }
}

__device__ __forceinline__ void gemm2_accum(const unsigned short* sH,
    const unsigned short* __restrict__ W2T, f32x4 (&o)[2][4],
    const int w, const int lr, const int lq)
{
  #pragma unroll
  for (int i2=0; i2<2; ++i2){
    const int ct2 = 2*w + i2;
    if (ct2 < 7){
      bf16x8 b2[8];
      #pragma unroll
      for (int kk=0; kk<8; ++kk)
        b2[kk] = *reinterpret_cast<const bf16x8*>(W2T + (size_t)(ct2*16+lr)*256 + kk*32 + lq*8);
      #pragma unroll
      for (int nt=0; nt<4; ++nt){
        const int row = nt*16 + lr;
        #pragma unroll
        for (int kk=0; kk<8; ++kk){
          const bf16x8 a2 = *reinterpret_cast<const bf16x8*>(
              (const char*)sH + row*512 + ((kk*64 + lq*16) ^ ((row&7)<<4)));
          o[i2][nt] = mfma16(a2, b2[kk], o[i2][nt]);
        }
      }
    }
  }
}

// ---------------- Fused kernel: attention -> right (LDS) -> 2-branch MFMA MLP ----------------
__global__ __launch_bounds__(256) void gamlp_fused(
    const float* __restrict__ feat, const float* __restrict__ label,
    const float* __restrict__ Watt, const float* __restrict__ batt,
    const unsigned short* __restrict__ Wo1T, const float* __restrict__ bo1, const float* __restrict__ aop,
    const unsigned short* __restrict__ Wo2T, const float* __restrict__ bo2,
    const unsigned short* __restrict__ Wl1T, const float* __restrict__ bl1, const float* __restrict__ alp,
    const unsigned short* __restrict__ Wl2T, const float* __restrict__ bl2,
    float* __restrict__ out)
{
  __shared__ __align__(16) unsigned short sA[64*128];   // 16 KB: right / label tile (swizzled bf16)
  __shared__ __align__(16) unsigned short sH[64*256];   // 32 KB: h tile (swizzled bf16) / f32 out bounce
  const int t = threadIdx.x;
  const int w = t >> 6, lane = t & 63, lr = lane & 15, lq = lane >> 4;
  const int nl = lq, fl = lr;                           // attn roles
  const size_t nb = (size_t)blockIdx.x * 64;
  const float ao = aop[0], al = alp[0];

  // ---------- Phase A: hop attention for 64 nodes (4 nodes/wave/iter, 4 iters) ----------
  const float4 w1a = *reinterpret_cast<const float4*>(Watt + fl*4);
  const float4 w1b = *reinterpret_cast<const float4*>(Watt + 64 + fl*4);
  const float4 w2a = *reinterpret_cast<const float4*>(Watt + FF + fl*4);
  const float4 w2b = *reinterpret_cast<const float4*>(Watt + FF + 64 + fl*4);
  const float batt0 = batt[0];

  #pragma unroll 1
  for (int it=0; it<4; ++it){
    const int row = w*16 + it*4 + nl;
    const float* fp = feat + (nb + row)*FF;
    float p1[NHOP], p2[NHOP];
    bf16x8 fbf[NHOP];
    #pragma unroll
    for (int i=0;i<NHOP;i++){
      const float* hp = fp + (size_t)i*((size_t)NN*FF);
      const float4 va = *reinterpret_cast<const float4*>(hp + fl*4);
      const float4 vb = *reinterpret_cast<const float4*>(hp + 64 + fl*4);
      p1[i] = va.x*w1a.x + va.y*w1a.y + va.z*w1a.z + va.w*w1a.w
            + vb.x*w1b.x + vb.y*w1b.y + vb.z*w1b.z + vb.w*w1b.w;
      p2[i] = va.x*w2a.x + va.y*w2a.y + va.z*w2a.z + va.w*w2a.w
            + vb.x*w2b.x + vb.y*w2b.y + vb.z*w2b.z + vb.w*w2b.w;
      fbf[i][0]=f2bfs(va.x); fbf[i][1]=f2bfs(va.y); fbf[i][2]=f2bfs(va.z); fbf[i][3]=f2bfs(va.w);
      fbf[i][4]=f2bfs(vb.x); fbf[i][5]=f2bfs(vb.y); fbf[i][6]=f2bfs(vb.z); fbf[i][7]=f2bfs(vb.w);
    }
    // butterfly all-reduce within each 16-lane group
    #pragma unroll
    for (int m=8;m>0;m>>=1){
      #pragma unroll
      for (int i=0;i<NHOP;i++){
        p1[i] += __shfl_xor(p1[i], m, 64);
        p2[i] += __shfl_xor(p2[i], m, 64);
      }
    }
    // scalar recurrence (replicated across 16 lanes)
    float sc[NHOP];
    sc[0] = leakyf(p1[0] + p2[0] + batt0);
    #pragma unroll
    for (int i=1;i<NHOP;i++){
      float mx = sc[0];
      #pragma unroll
      for (int j=1;j<i;j++) mx = fmaxf(mx, sc[j]);
      float Z = 0.f, hs = 0.f;
      #pragma unroll
      for (int j=0;j<i;j++){
        const float e = __expf(sc[j]-mx);
        Z += e;
        hs = fmaf(e, p1[j], hs);
      }
      sc[i] = leakyf(hs/Z + p2[i] + batt0);
    }
    float mx = sc[0];
    #pragma unroll
    for (int j=1;j<NHOP;j++) mx = fmaxf(mx, sc[j]);
    float Z = 0.f;
    float e[NHOP];
    #pragma unroll
    for (int j=0;j<NHOP;j++){ e[j] = __expf(sc[j]-mx); Z += e[j]; }
    const float inv = 1.f/Z;
    float racc[8];
    #pragma unroll
    for (int u=0;u<8;u++) racc[u] = 0.f;
    #pragma unroll
    for (int j=0;j<NHOP;j++){
      const float a = e[j]*inv;
      #pragma unroll
      for (int u=0;u<8;u++) racc[u] = fmaf(a, bf2f(fbf[j][u]), racc[u]);
    }
    bf16x4 sa, sb;
    sa[0]=f2bfs(racc[0]); sa[1]=f2bfs(racc[1]); sa[2]=f2bfs(racc[2]); sa[3]=f2bfs(racc[3]);
    sb[0]=f2bfs(racc[4]); sb[1]=f2bfs(racc[5]); sb[2]=f2bfs(racc[6]); sb[3]=f2bfs(racc[7]);
    // swizzled LDS write: logical sA[row][col], byte = row*256 + (2*col ^ ((row&7)<<4))
    *reinterpret_cast<bf16x4*>((char*)sA + row*256 + ((fl*8) ^ ((row&7)<<4))) = sa;
    *reinterpret_cast<bf16x4*>((char*)sA + row*256 + ((128 + fl*8) ^ ((row&7)<<4))) = sb;
  }
  __syncthreads();   // B1: right tile complete in sA

  // init out accumulators with final biases
  f32x4 o[2][4];
  #pragma unroll
  for (int i2=0; i2<2; ++i2){
    const int ct2 = 2*w + i2;
    const int c2 = ct2*16 + lr;
    const float init = (ct2 < 7 && c2 < CCC) ? (bo2[c2] + bl2[c2]) : 0.f;
    #pragma unroll
    for (int nt=0; nt<4; ++nt) o[i2][nt] = (f32x4){init, init, init, init};
  }

  // ---------- branch 1 ----------
  gemm1(sA, sH, Wo1T, bo1, ao, w, lr, lq);
  __syncthreads();   // B2: sH ready; sA free

  // stage label -> sA (VMEM issued before GEMM2's MFMA so latency hides under it)
  {
    const int rw = t >> 2, q = t & 3;
    const float* lbase = label + (nb + rw)*CCC;
    #pragma unroll
    for (int u=0; u<8; ++u){
      const int c0 = q*32 + u*4;
      bf16x4 pv = (bf16x4){0,0,0,0};
      if (c0 < CCC){
        const float4 v = *reinterpret_cast<const float4*>(lbase + c0);
        pv[0]=f2bfs(v.x); pv[1]=f2bfs(v.y); pv[2]=f2bfs(v.z); pv[3]=f2bfs(v.w);
      }
      *reinterpret_cast<bf16x4*>((char*)sA + rw*256 + ((2*c0) ^ ((rw&7)<<4))) = pv;
    }
  }
  gemm2_accum(sH, Wo2T, o, w, lr, lq);
  __syncthreads();   // B3: label staged; sH free

  // ---------- branch 2 ----------
  gemm1(sA, sH, Wl1T, bl1, al, w, lr, lq);
  __syncthreads();   // B4
  gemm2_accum(sH, Wl2T, o, w, lr, lq);
  __syncthreads();   // B5: sH free for f32 bounce

  // ---------- epilogue: bounce through LDS for coalesced stores ----------
  float* sF = reinterpret_cast<float*>(sH);
  #pragma unroll
  for (int i2=0; i2<2; ++i2){
    const int ct2 = 2*w + i2;
    const int c2 = ct2*16 + lr;
    if (ct2 < 7 && c2 < CCC){
      #pragma unroll
      for (int nt=0; nt<4; ++nt){
        #pragma unroll
        for (int j=0; j<4; ++j)
          sF[(nt*16 + lq*4 + j)*CCC + c2] = o[i2][nt][j];
      }
    }
  }
  __syncthreads();
  #pragma unroll
  for (int p=0; p<25; ++p){
    const int idx = p*256 + t;
    out[nb*CCC + idx] = sF[idx];
  }
}

extern "C" void kernel_launch(void* const* d_in, const int* in_sizes, int n_in,
                              void* d_out, int out_size, void* d_ws, size_t ws_size,
                              hipStream_t stream) {
  const float* feat  = (const float*)d_in[0];
  const float* label = (const float*)d_in[1];
  const float* Watt  = (const float*)d_in[2];
  const float* batt  = (const float*)d_in[3];
  const float* Wo1   = (const float*)d_in[4];
  const float* bo1   = (const float*)d_in[5];
  const float* aop   = (const float*)d_in[6];
  const float* Wo2   = (const float*)d_in[7];
  const float* bo2   = (const float*)d_in[8];
  const float* Wl1   = (const float*)d_in[9];
  const float* bl1   = (const float*)d_in[10];
  const float* alp   = (const float*)d_in[11];
  const float* Wl2   = (const float*)d_in[12];
  const float* bl2   = (const float*)d_in[13];
  float* out = (float*)d_out;

  unsigned short* Wo1T = (unsigned short*)d_ws;            // [256][128]
  unsigned short* Wl1T = Wo1T + 256*128;                   // [256][128]
  unsigned short* Wo2T = Wl1T + 256*128;                   // [112][256]
  unsigned short* Wl2T = Wo2T + 112*256;                   // [112][256]

  prep_weights<<<128, 256, 0, stream>>>(Wo1, Wl1, Wo2, Wl2, Wo1T, Wl1T, Wo2T, Wl2T);
  gamlp_fused<<<NN/64, 256, 0, stream>>>(feat, label, Watt, batt,
                                         Wo1T, bo1, aop, Wo2T, bo2,
                                         Wl1T, bl1, alp, Wl2T, bl2, out);
}